// Round 2
// baseline (1788.680 us; speedup 1.0000x reference)
//
#include <hip/hip_runtime.h>

// Cost-volume block: f1n = l2norm_C(f1); hori/verti 9-offset correlations vs f2,
// mean over C, leaky_relu(0.01), concat -> [B, 18, H, W].
// B=256, C=64, H=W=64, sr=4.
//
// R2: single-barrier-per-chunk software pipeline, double-buffered LDS (CCH=2).
// Every global load batch is covered by one compute phase before its waitcnt;
// __syncthreads drains vmcnt anyway, so no load spans more than one barrier.

constexpr int SR   = 4;
constexpr int NOFF = 2 * SR + 1;     // 9
constexpr int Bb   = 256;
constexpr int Cc   = 64;
constexpr int Hh   = 64;
constexpr int Ww   = 64;
constexpr int BH   = 16;             // h rows per block
constexpr int BAND = BH + 2 * SR;    // 24 staged f2 rows
constexpr int RP   = Ww + 2 * SR;    // 72 padded row stride
constexpr int CCH  = 2;              // channels per chunk (per LDS buffer)
constexpr int NCHUNK = Cc / CCH;     // 32
constexpr int BUF_FLOATS = CCH * BAND * RP;  // 3456 floats = 13824 B per buffer
constexpr int CH_STRIDE  = Hh * Ww;          // 4096 floats per channel
constexpr int CHUNK_STRIDE = CCH * CH_STRIDE; // 8192 floats per chunk

__device__ __forceinline__ float lrelu(float x) {
    return fmaxf(x, 0.01f * x);   // exact leaky relu, slope 0.01
}

__global__ __launch_bounds__(256, 4)
void cv_kernel(const float* __restrict__ f1, const float* __restrict__ f2,
               float* __restrict__ out)
{
    __shared__ float lds[2 * BUF_FLOATS];   // 27648 B, two buffers

    const int t  = threadIdx.x;
    const int tx = t & 15;          // w-granule (4 floats)
    const int ty = t >> 4;          // h row within tile
    const int b  = blockIdx.x;
    const int h0 = blockIdx.y * BH;
    const int h  = h0 + ty;

    // Zero horizontal pad granules of BOTH buffers once (never overwritten).
    if (t < 2 * CCH * BAND * 2) {   // 192
        const int pr = t >> 1, side = t & 1;
        const int r  = pr % BAND;
        const int c  = (pr / BAND) & 1;
        const int bu = pr / (BAND * CCH);
        *reinterpret_cast<float4*>(
            &lds[bu * BUF_FLOATS + (c * BAND + r) * RP + (side ? RP - 4 : 0)]) =
            make_float4(0.f, 0.f, 0.f, 0.f);
    }

    float hacc[NOFF][4], vacc[NOFF][4], nsq[4];
#pragma unroll
    for (int d = 0; d < NOFF; ++d)
#pragma unroll
        for (int q = 0; q < 4; ++q) { hacc[d][q] = 0.f; vacc[d][q] = 0.f; }
#pragma unroll
    for (int q = 0; q < 4; ++q) nsq[q] = 0.f;

    // Fixed per-thread staging geometry: 3 granules per chunk.
    const float* pk[3]; int ldsoff[3]; bool val[3];
#pragma unroll
    for (int k = 0; k < 3; ++k) {
        const int g   = t + 256 * k;          // [0, 768)
        const int c   = g / (BAND * 16);      // 0..1
        const int rem = g - c * (BAND * 16);
        const int r   = rem >> 4;
        const int gc  = rem & 15;
        const int row = h0 - SR + r;
        val[k]    = (row >= 0) && (row < Hh);
        pk[k]     = f2 + (((size_t)b * Cc + c) * Hh + (val[k] ? row : 0)) * Ww + 4 * gc;
        ldsoff[k] = (c * BAND + r) * RP + SR + 4 * gc;
    }
    const float* f1p = f1 + (((size_t)b * Cc) * Hh + h) * Ww + 4 * tx;

    float4 sv[3], fA[2], fB[2];

    auto GF2 = [&](int m) {                  // gather f2 chunk m -> sv
#pragma unroll
        for (int k = 0; k < 3; ++k)
            sv[k] = val[k] ? *reinterpret_cast<const float4*>(pk[k] + (size_t)m * CHUNK_STRIDE)
                           : make_float4(0.f, 0.f, 0.f, 0.f);
    };
    auto WR = [&](int bu) {                  // sv -> LDS buffer bu
#pragma unroll
        for (int k = 0; k < 3; ++k)
            *reinterpret_cast<float4*>(&lds[bu * BUF_FLOATS + ldsoff[k]]) = sv[k];
    };
    auto GF1 = [&](float4* F, int m) {       // f1 chunk m -> F[0..1]
        F[0] = *reinterpret_cast<const float4*>(f1p + (size_t)m * CHUNK_STRIDE);
        F[1] = *reinterpret_cast<const float4*>(f1p + (size_t)m * CHUNK_STRIDE + CH_STRIDE);
    };
    auto COMP = [&](int bu, const float4* F) {   // consume chunk in buffer bu
        const float* Lb = &lds[bu * BUF_FLOATS];
#pragma unroll
        for (int c = 0; c < CCH; ++c) {
            const float4 av = F[c];
            nsq[0] += av.x * av.x; nsq[1] += av.y * av.y;
            nsq[2] += av.z * av.z; nsq[3] += av.w * av.w;

            const float* rp_ = Lb + (c * BAND + ty + SR) * RP;
            float win[12];
            *reinterpret_cast<float4*>(&win[0]) = *reinterpret_cast<const float4*>(rp_ + 4 * tx);
            *reinterpret_cast<float4*>(&win[4]) = *reinterpret_cast<const float4*>(rp_ + 4 * tx + 4);
            *reinterpret_cast<float4*>(&win[8]) = *reinterpret_cast<const float4*>(rp_ + 4 * tx + 8);
#pragma unroll
            for (int d = 0; d < NOFF; ++d) {
                hacc[d][0] += av.x * win[d];
                hacc[d][1] += av.y * win[d + 1];
                hacc[d][2] += av.z * win[d + 2];
                hacc[d][3] += av.w * win[d + 3];
            }
#pragma unroll
            for (int d = 0; d < NOFF; ++d) {
                const float4 v = *reinterpret_cast<const float4*>(
                    Lb + (c * BAND + ty + d) * RP + SR + 4 * tx);
                vacc[d][0] += av.x * v.x; vacc[d][1] += av.y * v.y;
                vacc[d][2] += av.z * v.z; vacc[d][3] += av.w * v.w;
            }
        }
    };

    // ---- pipeline ----
    GF2(0); GF1(fA, 0);
    WR(0);
    __syncthreads();
    GF2(1);

#pragma unroll 1
    for (int it = 0; it < 15; ++it) {
        const int m = 2 * it;
        GF1(fB, m + 1);
        COMP(0, fA);            // chunk m
        WR(1);                  // stage chunk m+1 (covered by COMP)
        __syncthreads();
        __builtin_amdgcn_sched_barrier(0);
        GF2(m + 2);
        GF1(fA, m + 2);
        COMP(1, fB);            // chunk m+1
        WR(0);                  // stage chunk m+2
        __syncthreads();
        __builtin_amdgcn_sched_barrier(0);
        GF2(m + 3);
    }
    // state: buf0 = chunk 30, sv = chunk 31 (in flight), fA = f1 chunk 30
    GF1(fB, 31);
    COMP(0, fA);                // chunk 30
    WR(1);
    __syncthreads();
    COMP(1, fB);                // chunk 31

    // ---- epilogue: scale by 1/(C * max(||f1||, eps)), leaky relu, store ----
    float sc[4];
#pragma unroll
    for (int q = 0; q < 4; ++q)
        sc[q] = 1.0f / (64.0f * fmaxf(sqrtf(nsq[q]), 1e-12f));

    float* op = out + (((size_t)b * (2 * NOFF)) * Hh + h) * Ww + 4 * tx;
#pragma unroll
    for (int d = 0; d < NOFF; ++d) {
        float4 o;
        o.x = lrelu(hacc[d][0] * sc[0]);
        o.y = lrelu(hacc[d][1] * sc[1]);
        o.z = lrelu(hacc[d][2] * sc[2]);
        o.w = lrelu(hacc[d][3] * sc[3]);
        *reinterpret_cast<float4*>(op + (size_t)d * Hh * Ww) = o;
    }
#pragma unroll
    for (int d = 0; d < NOFF; ++d) {
        float4 o;
        o.x = lrelu(vacc[d][0] * sc[0]);
        o.y = lrelu(vacc[d][1] * sc[1]);
        o.z = lrelu(vacc[d][2] * sc[2]);
        o.w = lrelu(vacc[d][3] * sc[3]);
        *reinterpret_cast<float4*>(op + (size_t)(NOFF + d) * Hh * Ww) = o;
    }
}

extern "C" void kernel_launch(void* const* d_in, const int* in_sizes, int n_in,
                              void* d_out, int out_size, void* d_ws, size_t ws_size,
                              hipStream_t stream) {
    const float* f1 = (const float*)d_in[0];
    const float* f2 = (const float*)d_in[1];
    float* out = (float*)d_out;
    dim3 grid(Bb, Hh / BH);   // 256 x 4 = 1024 blocks
    cv_kernel<<<grid, dim3(256), 0, stream>>>(f1, f2, out);
}

// Round 3
// 132.552 us; speedup vs baseline: 13.4942x; 13.4942x over previous
//
#include <hip/hip_runtime.h>

// Cost-volume block: f1n = l2norm_C(f1); hori/verti 9-offset correlations vs f2,
// mean over C, leaky_relu(0.01), concat -> [B, 18, H, W].  B=256,C=64,H=W=64,sr=4.
//
// R3: 2-phase pipeline with global_load_lds (direct global->LDS, no VGPR
// round-trip), double-buffered unpadded LDS band. One barrier per chunk; stage
// of chunk m+1 is issued before compute of chunk m so its latency hides under
// compute. Vertical halo: OOB 4-row groups are never loaded (wave-uniform skip)
// and pre-zeroed once. Horizontal halo: edge taps zeroed via mask multiplies.

constexpr int SR   = 4;
constexpr int NOFF = 2 * SR + 1;     // 9
constexpr int Bb   = 256;
constexpr int Cc   = 64;
constexpr int Hh   = 64;
constexpr int Ww   = 64;
constexpr int BH   = 16;             // h rows per block
constexpr int BAND = BH + 2 * SR;    // 24 staged f2 rows
constexpr int ROWF = Ww;             // 64 floats/row, unpadded (256 B)
constexpr int CCH  = 2;              // channels per chunk
constexpr int NCHUNK = Cc / CCH;     // 32
constexpr int BUF_FLOATS = CCH * BAND * ROWF;   // 3072 floats = 12 KiB / buffer
constexpr int CH_STRIDE  = Hh * Ww;             // 4096
constexpr int CHUNK_STRIDE = CCH * CH_STRIDE;   // 8192

__device__ __forceinline__ float lrelu(float x) {
    return fmaxf(x, 0.01f * x);   // exact leaky relu, slope 0.01
}

__device__ __forceinline__ void gload16(const float* g, float* l) {
    __builtin_amdgcn_global_load_lds(
        (const __attribute__((address_space(1))) void*)g,
        (__attribute__((address_space(3))) void*)l, 16, 0, 0);
}

__global__ __launch_bounds__(256)
void cv_kernel(const float* __restrict__ f1, const float* __restrict__ f2,
               float* __restrict__ out)
{
    __shared__ float lds[2 * BUF_FLOATS];   // 24 KiB

    const int t  = threadIdx.x;
    const int tx = t & 15;          // w-granule (4 floats)
    const int ty = t >> 4;          // h row within tile
    const int wv = t >> 6;          // wave id (0..3)
    const int ln = t & 63;          // lane id
    const int b  = blockIdx.x;
    const int h0 = blockIdx.y * BH;
    const int h  = h0 + ty;

    // ---- staging geometry: 12 segments/chunk (2ch x 6 row-groups), 3/wave ----
    // segment = 4 rows x 64 floats = 1024 B = one global_load_lds(16) per wave.
    const float* gbase[3];
    int  lbase[3];
    bool segv[3];
#pragma unroll
    for (int k = 0; k < 3; ++k) {
        const int s  = wv * 3 + k;
        const int c  = s / 6;            // channel within chunk
        const int rg = s % 6;            // row group
        const int hr = h0 - SR + rg * 4; // first h row of group
        segv[k]  = (hr >= 0) && (hr + 3 < Hh);   // group fully in range
        gbase[k] = f2 + ((size_t)(b * Cc + c) * Hh + (segv[k] ? hr : 0) + (ln >> 4)) * Ww
                      + 4 * (ln & 15);
        lbase[k] = (c * BAND + rg * 4) * ROWF;   // wave-uniform LDS base (floats)
    }

    // ---- zero OOB rows once; staging skips them so they stay zero ----
    if (h0 == 0 || h0 == Hh - BH) {
        const int rg  = (h0 == 0) ? 0 : 5;
        const int col = t & 15, r = (t >> 4) & 3, c = (t >> 6) & 1, bu = t >> 7;
        *reinterpret_cast<float4*>(
            &lds[bu * BUF_FLOATS + (c * BAND + rg * 4 + r) * ROWF + 4 * col]) =
            make_float4(0.f, 0.f, 0.f, 0.f);
    }

    float hacc[NOFF][4], vacc[NOFF][4], nsq[4];
#pragma unroll
    for (int d = 0; d < NOFF; ++d)
#pragma unroll
        for (int q = 0; q < 4; ++q) { hacc[d][q] = 0.f; vacc[d][q] = 0.f; }
#pragma unroll
    for (int q = 0; q < 4; ++q) nsq[q] = 0.f;

    const float* f1p = f1 + ((size_t)(b * Cc) * Hh + h) * Ww + 4 * tx;
    const float m0 = (tx == 0)  ? 0.f : 1.f;   // left-edge tap mask
    const float m1 = (tx == 15) ? 0.f : 1.f;   // right-edge tap mask

    auto STAGE = [&](int bu, int m) {
#pragma unroll
        for (int k = 0; k < 3; ++k)
            if (segv[k])   // uniform within wave
                gload16(gbase[k] + (size_t)m * CHUNK_STRIDE,
                        &lds[bu * BUF_FLOATS + lbase[k]]);
    };
    auto GF1 = [&](float4* F, int m) {
        F[0] = *reinterpret_cast<const float4*>(f1p + (size_t)m * CHUNK_STRIDE);
        F[1] = *reinterpret_cast<const float4*>(f1p + (size_t)m * CHUNK_STRIDE + CH_STRIDE);
    };
    auto COMP = [&](int bu, const float4* F) {
        const float* Lb = &lds[bu * BUF_FLOATS];
#pragma unroll
        for (int c = 0; c < CCH; ++c) {
            const float4 av = F[c];
            nsq[0] += av.x * av.x; nsq[1] += av.y * av.y;
            nsq[2] += av.z * av.z; nsq[3] += av.w * av.w;

            const float* rp = Lb + (c * BAND + ty + SR) * ROWF + 4 * tx;
            float win[12];
            *reinterpret_cast<float4*>(&win[0]) = *reinterpret_cast<const float4*>(rp - 4);
            *reinterpret_cast<float4*>(&win[4]) = *reinterpret_cast<const float4*>(rp);
            *reinterpret_cast<float4*>(&win[8]) = *reinterpret_cast<const float4*>(rp + 4);
            win[0] *= m0; win[1] *= m0; win[2]  *= m0; win[3]  *= m0;
            win[8] *= m1; win[9] *= m1; win[10] *= m1; win[11] *= m1;
#pragma unroll
            for (int d = 0; d < NOFF; ++d) {
                hacc[d][0] += av.x * win[d];
                hacc[d][1] += av.y * win[d + 1];
                hacc[d][2] += av.z * win[d + 2];
                hacc[d][3] += av.w * win[d + 3];
            }
#pragma unroll
            for (int d = 0; d < NOFF; ++d) {
                const float4 v = *reinterpret_cast<const float4*>(
                    Lb + (c * BAND + ty + d) * ROWF + 4 * tx);
                vacc[d][0] += av.x * v.x; vacc[d][1] += av.y * v.y;
                vacc[d][2] += av.z * v.z; vacc[d][3] += av.w * v.w;
            }
        }
    };

    // ---- 2-phase pipeline, one barrier per chunk ----
    float4 fA[2], fB[2];
    STAGE(0, 0); GF1(fA, 0);
    __syncthreads();                 // drains stage-0 + zero-init writes

#pragma unroll 1
    for (int it = 0; it < 16; ++it) {
        const int m = 2 * it;
        STAGE(1, m + 1); GF1(fB, m + 1);   // issue next chunk early
        COMP(0, fA);                        // compute current (covers latency)
        __syncthreads();                    // drain -> buf1 ready, buf0 reusable
        if (it < 15) { STAGE(0, m + 2); GF1(fA, m + 2); }
        COMP(1, fB);
        __syncthreads();
    }

    // ---- epilogue: scale by 1/(C * max(||f1||, eps)), leaky relu, store ----
    float sc[4];
#pragma unroll
    for (int q = 0; q < 4; ++q)
        sc[q] = 1.0f / (64.0f * fmaxf(sqrtf(nsq[q]), 1e-12f));

    float* op = out + ((size_t)(b * 2 * NOFF) * Hh + h) * Ww + 4 * tx;
#pragma unroll
    for (int d = 0; d < NOFF; ++d) {
        float4 o;
        o.x = lrelu(hacc[d][0] * sc[0]);
        o.y = lrelu(hacc[d][1] * sc[1]);
        o.z = lrelu(hacc[d][2] * sc[2]);
        o.w = lrelu(hacc[d][3] * sc[3]);
        *reinterpret_cast<float4*>(op + (size_t)d * Hh * Ww) = o;
    }
#pragma unroll
    for (int d = 0; d < NOFF; ++d) {
        float4 o;
        o.x = lrelu(vacc[d][0] * sc[0]);
        o.y = lrelu(vacc[d][1] * sc[1]);
        o.z = lrelu(vacc[d][2] * sc[2]);
        o.w = lrelu(vacc[d][3] * sc[3]);
        *reinterpret_cast<float4*>(op + (size_t)(NOFF + d) * Hh * Ww) = o;
    }
}

extern "C" void kernel_launch(void* const* d_in, const int* in_sizes, int n_in,
                              void* d_out, int out_size, void* d_ws, size_t ws_size,
                              hipStream_t stream) {
    const float* f1 = (const float*)d_in[0];
    const float* f2 = (const float*)d_in[1];
    float* out = (float*)d_out;
    dim3 grid(Bb, Hh / BH);   // 256 x 4 = 1024 blocks
    cv_kernel<<<grid, dim3(256), 0, stream>>>(f1, f2, out);
}